// Round 1
// baseline (330.972 us; speedup 1.0000x reference)
//
#include <hip/hip_runtime.h>
#include <hip/hip_bf16.h>

// B=2, S=2048, D=1024, H=16, HD=64. fp32 in, fp32 out, bf16-tolerance threshold.
// Pipeline: convert->bf16 | QKV GEMM (mfma bf16) | RoPE | V-transpose | flash attn | out GEMM.

typedef unsigned short u16;
typedef short bf16x8 __attribute__((ext_vector_type(8)));
typedef float f32x4 __attribute__((ext_vector_type(4)));

__device__ __forceinline__ u16 f2bf(float f) {
    unsigned u = __builtin_bit_cast(unsigned, f);
    u += 0x7fffu + ((u >> 16) & 1u);   // RNE
    return (u16)(u >> 16);
}
__device__ __forceinline__ float bf2f(u16 h) {
    unsigned u = ((unsigned)h) << 16;
    return __builtin_bit_cast(float, u);
}

// ---------------- fp32 -> bf16 convert (4 elems/thread, exact grid) ----------------
__global__ __launch_bounds__(256) void f32_to_bf16_k(const float* __restrict__ in,
                                                     u16* __restrict__ out) {
    int i = (blockIdx.x * 256 + threadIdx.x) * 4;
    float4 v = *(const float4*)(in + i);
    uint2 o;
    o.x = (unsigned)f2bf(v.x) | ((unsigned)f2bf(v.y) << 16);
    o.y = (unsigned)f2bf(v.z) | ((unsigned)f2bf(v.w) << 16);
    *(uint2*)(out + i) = o;
}

// ---------------- bf16 GEMM: C[m][n] = sum_k A[m][k]*Bw[n][k] (+bias epilogue) -----
// m97 structure: 128x128 tile, BK=32, 4 waves (2x2) of 64x64, global_load_lds w=16.
// EPI==0: bf16 out, 3-segment bias (bq|bk|bv per 1024 cols). EPI==1: fp32 out, bias0.
template <int EPI>
__global__ __launch_bounds__(256) void gemm_bt(const u16* __restrict__ A,
                                               const u16* __restrict__ Bw,
                                               const float* __restrict__ bias0,
                                               const float* __restrict__ bias1,
                                               const float* __restrict__ bias2,
                                               u16* __restrict__ outB,
                                               float* __restrict__ outF,
                                               int M, int N, int K) {
    __shared__ __align__(16) u16 As[128 * 32];
    __shared__ __align__(16) u16 Bs[128 * 32];
    const int tid = threadIdx.x;
    const int lane = tid & 63;
    const int w = tid >> 6;
    const int wr = w >> 1, wc = w & 1;
    const int lr = lane & 15, lg = lane >> 4;
    const int nbn = N >> 7;
    const int m0 = (blockIdx.x / nbn) << 7;
    const int n0 = (blockIdx.x % nbn) << 7;

    f32x4 acc[4][4] = {};

    // staging: 512 16B-chunks per tensor; wave w iter i covers chunks [(w*2+i)*64, +64)
    const u16* aptr[2];
    const u16* bptr[2];
    int ldsoff[2];
#pragma unroll
    for (int i = 0; i < 2; ++i) {
        int c = (w * 2 + i) * 64 + lane;
        int row = c >> 2, kc = (c & 3) << 3;
        aptr[i] = A + (size_t)(m0 + row) * K + kc;
        bptr[i] = Bw + (size_t)(n0 + row) * K + kc;
        ldsoff[i] = (w * 2 + i) * 512;  // shorts
    }

    for (int k0 = 0; k0 < K; k0 += 32) {
#pragma unroll
        for (int i = 0; i < 2; ++i) {
            __builtin_amdgcn_global_load_lds(
                (const __attribute__((address_space(1))) void*)(aptr[i] + k0),
                (__attribute__((address_space(3))) void*)(As + ldsoff[i]), 16, 0, 0);
            __builtin_amdgcn_global_load_lds(
                (const __attribute__((address_space(1))) void*)(bptr[i] + k0),
                (__attribute__((address_space(3))) void*)(Bs + ldsoff[i]), 16, 0, 0);
        }
        __syncthreads();
        bf16x8 af[4], bfr[4];
#pragma unroll
        for (int i = 0; i < 4; ++i)
            af[i] = *(const bf16x8*)(As + (wr * 64 + i * 16 + lr) * 32 + lg * 8);
#pragma unroll
        for (int j = 0; j < 4; ++j)
            bfr[j] = *(const bf16x8*)(Bs + (wc * 64 + j * 16 + lr) * 32 + lg * 8);
#pragma unroll
        for (int i = 0; i < 4; ++i)
#pragma unroll
            for (int j = 0; j < 4; ++j)
                acc[i][j] = __builtin_amdgcn_mfma_f32_16x16x32_bf16(af[i], bfr[j],
                                                                    acc[i][j], 0, 0, 0);
        __syncthreads();
    }

#pragma unroll
    for (int i = 0; i < 4; ++i) {
        int mg = m0 + wr * 64 + i * 16 + lg * 4;
#pragma unroll
        for (int j = 0; j < 4; ++j) {
            int ng = n0 + wc * 64 + j * 16 + lr;
            float bias;
            if (EPI == 0)
                bias = (ng < 1024) ? bias0[ng] : (ng < 2048) ? bias1[ng - 1024]
                                                             : bias2[ng - 2048];
            else
                bias = bias0[ng];
#pragma unroll
            for (int r = 0; r < 4; ++r) {
                float v = acc[i][j][r] + bias;
                if (EPI == 0)
                    outB[(size_t)(mg + r) * N + ng] = f2bf(v);
                else
                    outF[(size_t)(mg + r) * N + ng] = v;
            }
        }
    }
}

// ---------------- RoPE in-place on q,k halves of qkv[4096][3072] -------------------
// pair index p -> (row m, mat(q/k), head, i). x1=col i, x2=col i+32 within head.
__global__ __launch_bounds__(256) void rope_k(u16* qkv, const int* __restrict__ days) {
    int p = blockIdx.x * 256 + threadIdx.x;  // 4096*2*16*32 = 4194304 total
    int m = p >> 10;
    int r = p & 1023;
    int mat = r >> 9;
    int hh = (r >> 5) & 15;
    int i = r & 31;
    int d = days[m];
    int ad = d < 0 ? -d : d;
    float pos = (float)(ad > 2047 ? 2047 : ad);
    // inv_freq = 10000^(-i/32) = 2^(-i*log2(10000)/32)
    float inv = exp2f((float)i * -0.41524101186091903f);
    float f = pos * inv;
    float sn, cs;
    __sincosf(f, &sn, &cs);
    size_t base = (size_t)m * 3072 + mat * 1024 + hh * 64 + i;
    float x1 = bf2f(qkv[base]);
    float x2 = bf2f(qkv[base + 32]);
    qkv[base] = f2bf(x1 * cs - x2 * sn);
    qkv[base + 32] = f2bf(x2 * cs + x1 * sn);
}

// ---------------- V transpose: qkv v-region -> Vt[b,h,hd,s] ------------------------
__global__ __launch_bounds__(256) void v_transpose_k(const u16* __restrict__ qkv,
                                                     u16* __restrict__ vt) {
    __shared__ u16 tile[64][66];  // pad: row stride 132B = 33 banks (odd) -> conflict-free
    int st = blockIdx.x & 31;
    int bh = blockIdx.x >> 5;
    int b = bh >> 4, h = bh & 15;
    int s0 = st * 64;
    int t = threadIdx.x;
#pragma unroll
    for (int it = 0; it < 16; ++it) {
        int idx = it * 256 + t;
        int sr = idx >> 6, c = idx & 63;
        tile[sr][c] = qkv[(size_t)(b * 2048 + s0 + sr) * 3072 + 2048 + h * 64 + c];
    }
    __syncthreads();
#pragma unroll
    for (int it = 0; it < 16; ++it) {
        int idx = it * 256 + t;
        int hd = idx >> 6, sc = idx & 63;
        vt[((size_t)(bh * 64 + hd)) * 2048 + s0 + sc] = tile[sc][hd];
    }
}

// ---------------- flash attention with decay + causal mask -------------------------
// Block = 4 independent waves; wave owns 16 q-rows. KV tile = 32 keys.
// QK^T: D-frag row = q (lg*4+r), col = key (lr)  [m89-verified C/D layout].
// P transposed to A-layout through per-wave LDS; PV B-frag from Vt (contiguous in s).
__global__ __launch_bounds__(256) void attn_k(const u16* __restrict__ qkv,
                                              const u16* __restrict__ vt,
                                              const int* __restrict__ days,
                                              const float* __restrict__ decay_p,
                                              u16* __restrict__ attn_out) {
    __shared__ __align__(16) u16 P_lds[4][16 * 32];
    const int tid = threadIdx.x;
    const int lane = tid & 63;
    const int w = tid >> 6;
    const int lr = lane & 15, lg = lane >> 4;
    const int qt4 = blockIdx.x & 31;   // S/64
    const int bh = blockIdx.x >> 5;    // b*16+h
    const int b = bh >> 4, h = bh & 15;
    const int qbase = qt4 * 64 + w * 16;
    const float rate = decay_p[0];

    const u16* qmat = qkv + (size_t)b * 2048 * 3072 + h * 64;
    const u16* kmat = qmat + 1024;
    const u16* vtm = vt + (size_t)bh * 64 * 2048;
    const int* db = days + b * 2048;

    bf16x8 aq[2];
    {
        const u16* qp = qmat + (size_t)(qbase + lr) * 3072 + lg * 8;
        aq[0] = *(const bf16x8*)qp;
        aq[1] = *(const bf16x8*)(qp + 32);
    }
    float dq[4];
#pragma unroll
    for (int r = 0; r < 4; ++r) dq[r] = (float)db[qbase + lg * 4 + r];

    float m_r[4] = {-INFINITY, -INFINITY, -INFINITY, -INFINITY};
    float l_r[4] = {0.f, 0.f, 0.f, 0.f};
    f32x4 acc[4] = {};

    const int ktiles = (qbase + 15) / 32 + 1;
    for (int kt = 0; kt < ktiles; ++kt) {
        const int k0 = kt * 32;
        f32x4 sfr[2];
        float dkf[2];
#pragma unroll
        for (int sub = 0; sub < 2; ++sub) {
            const int krow = k0 + sub * 16 + lr;
            const u16* kp = kmat + (size_t)krow * 3072 + lg * 8;
            bf16x8 bk0 = *(const bf16x8*)kp;
            bf16x8 bk1 = *(const bf16x8*)(kp + 32);
            f32x4 t = {};
            t = __builtin_amdgcn_mfma_f32_16x16x32_bf16(aq[0], bk0, t, 0, 0, 0);
            t = __builtin_amdgcn_mfma_f32_16x16x32_bf16(aq[1], bk1, t, 0, 0, 0);
            sfr[sub] = t;
            dkf[sub] = (float)db[krow];
        }
        float fr_[4];
        float p[2][4];
#pragma unroll
        for (int r = 0; r < 4; ++r) {
            const int qg = qbase + lg * 4 + r;
            float rowmax = -INFINITY;
#pragma unroll
            for (int sub = 0; sub < 2; ++sub) {
                const int kg = k0 + sub * 16 + lr;
                float v = sfr[sub][r] * 0.125f;
                v *= __expf(-rate * fabsf(dq[r] - dkf[sub]));
                v = (kg <= qg) ? v : -INFINITY;
                p[sub][r] = v;
                rowmax = fmaxf(rowmax, v);
            }
#pragma unroll
            for (int off = 1; off < 16; off <<= 1)
                rowmax = fmaxf(rowmax, __shfl_xor(rowmax, off));
            const float mn = fmaxf(m_r[r], rowmax);
            const float fr = __expf(m_r[r] - mn);  // -inf -> 0
            float sum = 0.f;
#pragma unroll
            for (int sub = 0; sub < 2; ++sub) {
                const float pv = __expf(p[sub][r] - mn);
                p[sub][r] = pv;
                sum += pv;
            }
#pragma unroll
            for (int off = 1; off < 16; off <<= 1) sum += __shfl_xor(sum, off);
            l_r[r] = l_r[r] * fr + sum;
            m_r[r] = mn;
            fr_[r] = fr;
        }
        // P (D-layout) -> LDS -> A-layout for PV
#pragma unroll
        for (int r = 0; r < 4; ++r)
#pragma unroll
            for (int sub = 0; sub < 2; ++sub)
                P_lds[w][(lg * 4 + r) * 32 + sub * 16 + lr] = f2bf(p[sub][r]);
        bf16x8 pa = *(const bf16x8*)&P_lds[w][lr * 32 + lg * 8];
#pragma unroll
        for (int c = 0; c < 4; ++c) {
#pragma unroll
            for (int r = 0; r < 4; ++r) acc[c][r] *= fr_[r];
            bf16x8 bv =
                *(const bf16x8*)(vtm + (size_t)(c * 16 + lr) * 2048 + k0 + lg * 8);
            acc[c] = __builtin_amdgcn_mfma_f32_16x16x32_bf16(pa, bv, acc[c], 0, 0, 0);
        }
    }
#pragma unroll
    for (int c = 0; c < 4; ++c)
#pragma unroll
        for (int r = 0; r < 4; ++r) {
            const int qg = qbase + lg * 4 + r;
            attn_out[(size_t)(b * 2048 + qg) * 1024 + h * 64 + c * 16 + lr] =
                f2bf(acc[c][r] / l_r[r]);
        }
}

// ---------------- launch -----------------------------------------------------------
extern "C" void kernel_launch(void* const* d_in, const int* in_sizes, int n_in,
                              void* d_out, int out_size, void* d_ws, size_t ws_size,
                              hipStream_t stream) {
    const float* x = (const float*)d_in[0];
    const float* Wq = (const float*)d_in[1];
    const float* bq = (const float*)d_in[2];
    const float* Wk = (const float*)d_in[3];
    const float* bk = (const float*)d_in[4];
    const float* Wv = (const float*)d_in[5];
    const float* bv = (const float*)d_in[6];
    const float* Wo = (const float*)d_in[7];
    const float* bo = (const float*)d_in[8];
    const float* decay = (const float*)d_in[9];
    // d_in[10] = mask (tril by construction; causal implemented directly)
    const int* days = (const int*)d_in[11];
    float* out = (float*)d_out;

    char* ws = (char*)d_ws;
    u16* xb = (u16*)(ws);                   //  8 MB: x bf16 [4096][1024]
    u16* wqkv = (u16*)(ws + 8388608);       //  6 MB: [Wq;Wk;Wv] bf16 [3072][1024]
    u16* wo = (u16*)(ws + 14680064);        //  2 MB: Wo bf16 [1024][1024]
    u16* qkvb = (u16*)(ws + 16777216);      // 24 MB: qkv bf16 [4096][3072]
    u16* vtb = (u16*)(ws + 41943040);       //  8 MB: Vt bf16 [32][64][2048]
    u16* attb = (u16*)(ws + 50331648);      //  8 MB: attn out bf16 [4096][1024]

    f32_to_bf16_k<<<4096, 256, 0, stream>>>(x, xb);
    f32_to_bf16_k<<<1024, 256, 0, stream>>>(Wq, wqkv);
    f32_to_bf16_k<<<1024, 256, 0, stream>>>(Wk, wqkv + 1048576);
    f32_to_bf16_k<<<1024, 256, 0, stream>>>(Wv, wqkv + 2097152);
    f32_to_bf16_k<<<1024, 256, 0, stream>>>(Wo, wo);

    gemm_bt<0><<<768, 256, 0, stream>>>(xb, wqkv, bq, bk, bv, qkvb, nullptr, 4096,
                                        3072, 1024);
    rope_k<<<16384, 256, 0, stream>>>(qkvb, days);
    v_transpose_k<<<1024, 256, 0, stream>>>(qkvb, vtb);
    attn_k<<<1024, 256, 0, stream>>>(qkvb, vtb, days, decay, attb);
    gemm_bt<1><<<256, 256, 0, stream>>>(attb, wo, bo, nullptr, nullptr, nullptr, out,
                                        4096, 1024, 1024);
}